// Round 4
// baseline (133.038 us; speedup 1.0000x reference)
//
#include <hip/hip_runtime.h>

// Problem constants (fixed by the reference).
#define BATCH 16384
#define DIN   128
#define HIDN  16
#define NNODE 255
#define NLEAF 256

typedef _Float16 half8 __attribute__((ext_vector_type(8)));
typedef float   float4v __attribute__((ext_vector_type(4)));

// ---------------- pack x -> f16 B-operand fragments ----------------
// B-frag layout for v_mfma_f32_16x16x32_f16: lane L holds B[k=(L>>4)*8+j][n=L&15].
// ws layout: [bt(1024)][kc(4)][lane(64)] -> half8 (16B)
__global__ __launch_bounds__(256) void k_pack_x(const float* __restrict__ x, half8* __restrict__ xp) {
    int gid  = blockIdx.x * 256 + threadIdx.x;   // 1024*4*64 = 262144 total
    int lane = gid & 63;
    int kc   = (gid >> 6) & 3;
    int bt   = gid >> 8;
    const float4* src = (const float4*)(x + (size_t)(bt * 16 + (lane & 15)) * DIN + kc * 32 + ((lane >> 4) * 8));
    float4 v0 = src[0], v1 = src[1];
    half8 v;
    v[0] = (_Float16)v0.x; v[1] = (_Float16)v0.y; v[2] = (_Float16)v0.z; v[3] = (_Float16)v0.w;
    v[4] = (_Float16)v1.x; v[5] = (_Float16)v1.y; v[6] = (_Float16)v1.z; v[7] = (_Float16)v1.w;
    xp[gid] = v;
}

// ---------------- pack W1 -> f16 A-operand fragments (LDS-staged) ----------------
// A-frag layout: lane L holds A[m=L&15][k=(L>>4)*8+j]; m = hidden h, k = input i.
// One block per node: coalesced read of 2048 floats -> LDS (pad 17) -> frag gather.
__global__ __launch_bounds__(256) void k_pack_w1(const float* __restrict__ w1, half8* __restrict__ w1p) {
    __shared__ float w[DIN * 17];                 // [k][m] padded: w[k*17+m]
    int n = blockIdx.x;
    int t = threadIdx.x;
    const float4* src = (const float4*)(w1 + (size_t)n * (DIN * HIDN)) + t * 2;
    float4 a0 = src[0], a1 = src[1];
    int base = t * 8;
#pragma unroll
    for (int e = 0; e < 4; ++e) {
        int idx0 = base + e, idx1 = base + 4 + e;
        float v0 = (&a0.x)[e], v1 = (&a1.x)[e];
        w[(idx0 >> 4) * 17 + (idx0 & 15)] = v0;
        w[(idx1 >> 4) * 17 + (idx1 & 15)] = v1;
    }
    __syncthreads();
    int L  = t & 63;
    int kc = t >> 6;
    int m  = L & 15;
    int k0 = kc * 32 + (L >> 4) * 8;
    half8 v;
#pragma unroll
    for (int j = 0; j < 8; ++j) v[j] = (_Float16)w[(k0 + j) * 17 + m];
    w1p[(size_t)n * 256 + t] = v;
}

// ---------------- MLP: p_ws[n][b] = sigmoid(relu(x@W1+b1)@W2+b2) ----------------
// __launch_bounds__(256,4): grid gives only 4.25 waves/SIMD, so cap occupancy at 4
// waves/EU -> 128 VGPR budget -> bq[4][4] (64 VGPRs) stays RESIDENT across the node
// loop. (Plain bounds gave VGPR_Count=56: compiler re-loaded all 16 xp fragments
// every node iteration = ~1 GB of L2 traffic.) The asm memory fence pins the loads
// above the loop so they can't be sunk back in.
__global__ __launch_bounds__(256, 4) void k_mlp(const half8* __restrict__ xp, const half8* __restrict__ w1p,
                                                const float* __restrict__ b1, const float* __restrict__ w2,
                                                const float* __restrict__ b2, float* __restrict__ p_ws) {
    int wave = threadIdx.x >> 6;
    int lane = threadIdx.x & 63;
    int q    = lane >> 4;       // quad: h = q*4 + r
    int c    = lane & 15;       // batch column within tile
    int bt0  = blockIdx.x * 16 + wave * 4;
    int n0   = blockIdx.y * 15;

    half8 bq[4][4];
#pragma unroll
    for (int t = 0; t < 4; ++t)
#pragma unroll
        for (int kc = 0; kc < 4; ++kc)
            bq[t][kc] = xp[(size_t)((bt0 + t) * 4 + kc) * 64 + lane];
    asm volatile("" ::: "memory");   // pin bq loads before the node loop

    for (int i = 0; i < 15; ++i) {
        int n = n0 + i;
        half8 a[4];
#pragma unroll
        for (int kc = 0; kc < 4; ++kc) a[kc] = w1p[(size_t)(n * 4 + kc) * 64 + lane];
        float4 b1f = ((const float4*)(b1 + n * HIDN))[q];
        float4 w2f = ((const float4*)(w2 + n * HIDN))[q];
        float  b2v = b2[n];
#pragma unroll
        for (int t = 0; t < 4; ++t) {
            float4v acc = {b1f.x, b1f.y, b1f.z, b1f.w};   // bias folded into acc init
#pragma unroll
            for (int kc = 0; kc < 4; ++kc)
                acc = __builtin_amdgcn_mfma_f32_16x16x32_f16(a[kc], bq[t][kc], acc, 0, 0, 0);
            float s = fmaf(fmaxf(acc[0], 0.f), w2f.x,
                      fmaf(fmaxf(acc[1], 0.f), w2f.y,
                      fmaf(fmaxf(acc[2], 0.f), w2f.z,
                           fmaxf(acc[3], 0.f) * w2f.w)));
            s += __shfl_xor(s, 16, 64);
            s += __shfl_xor(s, 32, 64);
            float logit = s + b2v;
            float pv = __builtin_amdgcn_rcpf(1.f + __builtin_amdgcn_exp2f(-1.44269504088896f * logit));
            if (lane < 16)
                p_ws[(size_t)n * BATCH + (bt0 + t) * 16 + c] = pv;   // coalesced full-line store
        }
    }
}

// ---------------- tree scan: reads p_ws[n][b], writes all outputs coalesced ----------------
// Block = 256 thr = 4 waves, 32 batch rows. Stage p into LDS [row][n] (stride 257),
// then per-row scan (8 rows/wave), coalesced p_out/pp/nr/h stores.
__global__ __launch_bounds__(256) void k_tree(const float* __restrict__ p_ws, const float* __restrict__ leaf,
                                              float* __restrict__ h_out, float* __restrict__ pp_out,
                                              float* __restrict__ p_out, float* __restrict__ nr_out) {
    __shared__ float sp[32][NNODE + 2];           // stride 257: bank = (row + n) % 32
    int wv   = threadIdx.x >> 6;
    int lane = threadIdx.x & 63;
    int b0   = blockIdx.x * 32;
    int t    = threadIdx.x;

    // stage: idx = n*32 + b_local; 256 threads -> 8 n-rows x 32 b per iteration
    for (int i = 0; i < 32; ++i) {
        int idx = i * 256 + t;
        if (idx < NNODE * 32) {
            int n = idx >> 5, bl = idx & 31;
            sp[bl][n] = p_ws[(size_t)n * BATCH + b0 + bl];
        }
    }
    __syncthreads();

    // coalesced p_out copy: rows b0..b0+31 contiguous in [b][n] layout
    for (int r = 0; r < 32; ++r)
        if (t < NNODE)
            p_out[(size_t)(b0 + r) * NNODE + t] = sp[r][t];

    // tree scan: 8 rows per wave; lane L owns leaves 4L..4L+3
    for (int rr = 0; rr < 8; ++rr) {
        int i = wv * 8 + rr;
        int b = b0 + i;
        const float* P = &sp[i][0];
        float* nr = nr_out + (size_t)b * NNODE;

        float pref = 1.f;
#pragma unroll
        for (int l = 0; l < 6; ++l) {
            if ((lane & ((1 << (6 - l)) - 1)) == 0) nr[(1 << l) - 1 + (lane >> (6 - l))] = pref;
            float pv  = P[(1 << l) - 1 + (lane >> (6 - l))];
            int  bit  = (lane >> (5 - l)) & 1;
            pref *= bit ? pv : (1.f - pv);
        }
        nr[63 + lane] = pref;
        float p6 = P[63 + lane];
        float pl = pref * (1.f - p6);
        float pr = pref * p6;
        nr[127 + 2 * lane] = pl;
        nr[128 + 2 * lane] = pr;
        float p7a = P[127 + 2 * lane];
        float p7b = P[128 + 2 * lane];
        float4 pp;
        pp.x = pl * (1.f - p7a);
        pp.y = pl * p7a;
        pp.z = pr * (1.f - p7b);
        pp.w = pr * p7b;
        *(float4*)(pp_out + (size_t)b * NLEAF + 4 * lane) = pp;
        const float4 lf = *(const float4*)(leaf + 4 * lane);
        float hs = pp.x * lf.x + pp.y * lf.y + pp.z * lf.z + pp.w * lf.w;
#pragma unroll
        for (int off = 1; off < 64; off <<= 1) hs += __shfl_xor(hs, off, 64);
        if (lane == 0) h_out[b] = hs;
    }
}

extern "C" void kernel_launch(void* const* d_in, const int* in_sizes, int n_in,
                              void* d_out, int out_size, void* d_ws, size_t ws_size,
                              hipStream_t stream) {
    const float* x    = (const float*)d_in[0];
    const float* W1   = (const float*)d_in[1];
    const float* b1   = (const float*)d_in[2];
    const float* W2   = (const float*)d_in[3];
    const float* b2   = (const float*)d_in[4];
    const float* leaf = (const float*)d_in[5];

    float* out    = (float*)d_out;
    float* h_out  = out;                                   // [16384]
    float* pp_out = out + BATCH;                           // [16384*256]
    float* p_out  = pp_out + (size_t)BATCH * NLEAF;        // [16384*255]
    float* nr_out = p_out + (size_t)BATCH * NNODE;         // [16384*255]

    // workspace: 4 MB xp + ~1 MB w1p + 16.7 MB transposed p  (~22 MB total)
    half8* xp   = (half8*)d_ws;
    half8* w1p  = xp + (size_t)1024 * 4 * 64;
    float* p_ws = (float*)(w1p + (size_t)NNODE * 256);

    hipLaunchKernelGGL(k_pack_x,  dim3(1024),  dim3(256), 0, stream, x, xp);
    hipLaunchKernelGGL(k_pack_w1, dim3(NNODE), dim3(256), 0, stream, W1, w1p);
    hipLaunchKernelGGL(k_mlp,     dim3(64, 17), dim3(256), 0, stream, xp, w1p, b1, W2, b2, p_ws);
    hipLaunchKernelGGL(k_tree,    dim3(BATCH / 32), dim3(256), 0, stream,
                       p_ws, leaf, h_out, pp_out, p_out, nr_out);
}

// Round 5
// 131.522 us; speedup vs baseline: 1.0115x; 1.0115x over previous
//
#include <hip/hip_runtime.h>

// Problem constants (fixed by the reference).
#define BATCH 16384
#define DIN   128
#define HIDN  16
#define NNODE 255
#define NLEAF 256
#define TR    16          // batch rows per tree block

typedef _Float16 half8 __attribute__((ext_vector_type(8)));
typedef float   float4v __attribute__((ext_vector_type(4)));

// 16-lane (DPP row) sum reduction: 4 rotate-adds, pure VALU, no LDS pipe.
__device__ __forceinline__ float row_reduce16(float x) {
    union U { float f; int i; } u, v;
    u.f = x; v.i = __builtin_amdgcn_update_dpp(0, u.i, 0x128, 0xF, 0xF, true); x += v.f; // row_ror:8
    u.f = x; v.i = __builtin_amdgcn_update_dpp(0, u.i, 0x124, 0xF, 0xF, true); x += v.f; // row_ror:4
    u.f = x; v.i = __builtin_amdgcn_update_dpp(0, u.i, 0x122, 0xF, 0xF, true); x += v.f; // row_ror:2
    u.f = x; v.i = __builtin_amdgcn_update_dpp(0, u.i, 0x121, 0xF, 0xF, true); x += v.f; // row_ror:1
    return x;
}

// ---------------- pack x -> f16 fragments ----------------
// Layout serves as MFMA A-operand: lane L holds A[m=L&15][k=(L>>4)*8+j], m=batch row, k=din.
__global__ __launch_bounds__(256) void k_pack_x(const float* __restrict__ x, half8* __restrict__ xp) {
    int gid  = blockIdx.x * 256 + threadIdx.x;   // 1024*4*64 = 262144 total
    int lane = gid & 63;
    int kc   = (gid >> 6) & 3;
    int bt   = gid >> 8;
    const float4* src = (const float4*)(x + (size_t)(bt * 16 + (lane & 15)) * DIN + kc * 32 + ((lane >> 4) * 8));
    float4 v0 = src[0], v1 = src[1];
    half8 v;
    v[0] = (_Float16)v0.x; v[1] = (_Float16)v0.y; v[2] = (_Float16)v0.z; v[3] = (_Float16)v0.w;
    v[4] = (_Float16)v1.x; v[5] = (_Float16)v1.y; v[6] = (_Float16)v1.z; v[7] = (_Float16)v1.w;
    xp[gid] = v;
}

// ---------------- pack W1 -> f16 fragments (LDS-staged) ----------------
// Layout serves as MFMA B-operand: lane L holds B[k=(L>>4)*8+j][n=L&15], k=din, n=hidden.
__global__ __launch_bounds__(256) void k_pack_w1(const float* __restrict__ w1, half8* __restrict__ w1p) {
    __shared__ float w[DIN * 17];                 // [k][m] padded: w[k*17+m]
    int n = blockIdx.x;
    int t = threadIdx.x;
    const float4* src = (const float4*)(w1 + (size_t)n * (DIN * HIDN)) + t * 2;
    float4 a0 = src[0], a1 = src[1];
    int base = t * 8;
#pragma unroll
    for (int e = 0; e < 4; ++e) {
        int idx0 = base + e, idx1 = base + 4 + e;
        float v0 = (&a0.x)[e], v1 = (&a1.x)[e];
        w[(idx0 >> 4) * 17 + (idx0 & 15)] = v0;
        w[(idx1 >> 4) * 17 + (idx1 & 15)] = v1;
    }
    __syncthreads();
    int L  = t & 63;
    int kc = t >> 6;
    int m  = L & 15;
    int k0 = kc * 32 + (L >> 4) * 8;
    half8 v;
#pragma unroll
    for (int j = 0; j < 8; ++j) v[j] = (_Float16)w[(k0 + j) * 17 + m];
    w1p[(size_t)n * 256 + t] = v;
}

// ---------------- MLP: p_ws[n][b] = LOGIT (sigmoid applied in k_tree) ----------------
// mfma(A=x, B=W1): C has m=batch=(lane>>4)*4+reg, n=hidden=lane&15. The h-reduction is
// a 16-lane DPP row reduce (pure VALU) instead of two serial cross-half shuffles.
// 2 tiles/wave, grid (128,17): 2176 blocks = 8.5 waves/SIMD offered, bounds(256,5).
__global__ __launch_bounds__(256, 5) void k_mlp(const half8* __restrict__ xp, const half8* __restrict__ w1p,
                                                const float* __restrict__ b1, const float* __restrict__ w2,
                                                const float* __restrict__ b2, float* __restrict__ p_ws) {
    int wv   = threadIdx.x >> 6;
    int lane = threadIdx.x & 63;
    int rg   = lane >> 4;       // row-group: batch rows rg*4 .. rg*4+3
    int hc   = lane & 15;       // hidden column
    int bt0  = blockIdx.x * 8 + wv * 2;
    int n0   = blockIdx.y * 15;

    half8 xa[2][4];
#pragma unroll
    for (int t = 0; t < 2; ++t)
#pragma unroll
        for (int kc = 0; kc < 4; ++kc)
            xa[t][kc] = xp[(size_t)((bt0 + t) * 4 + kc) * 64 + lane];
    asm volatile("" ::: "memory");

    for (int i = 0; i < 15; ++i) {
        int n = n0 + i;
        half8 wb[4];
#pragma unroll
        for (int kc = 0; kc < 4; ++kc) wb[kc] = w1p[(size_t)(n * 4 + kc) * 64 + lane];
        float b1v = b1[n * HIDN + hc];    // bias for this h, all 4 batch rows
        float w2v = w2[n * HIDN + hc];
        float b2v = b2[n];
#pragma unroll
        for (int t = 0; t < 2; ++t) {
            float4v acc = {b1v, b1v, b1v, b1v};
#pragma unroll
            for (int kc = 0; kc < 4; ++kc)
                acc = __builtin_amdgcn_mfma_f32_16x16x32_f16(xa[t][kc], wb[kc], acc, 0, 0, 0);
            float s0 = fmaxf(acc[0], 0.f) * w2v;
            float s1 = fmaxf(acc[1], 0.f) * w2v;
            float s2 = fmaxf(acc[2], 0.f) * w2v;
            float s3 = fmaxf(acc[3], 0.f) * w2v;
            s0 = row_reduce16(s0);
            s1 = row_reduce16(s1);
            s2 = row_reduce16(s2);
            s3 = row_reduce16(s3);
            if (hc == 0) {                // 4 lanes/wave store one full float4 each (64B line)
                float4 o = {s0 + b2v, s1 + b2v, s2 + b2v, s3 + b2v};
                *(float4*)(p_ws + (size_t)n * BATCH + (bt0 + t) * 16 + rg * 4) = o;
            }
        }
    }
}

// ---------------- tree scan: sigmoid + all outputs, coalesced ----------------
// Block = 256 thr, 16 batch rows, LDS 16.4 KB (grid 1024 -> 4 blocks/CU).
__global__ __launch_bounds__(256) void k_tree(const float* __restrict__ p_ws, const float* __restrict__ leaf,
                                              float* __restrict__ h_out, float* __restrict__ pp_out,
                                              float* __restrict__ p_out, float* __restrict__ nr_out) {
    __shared__ float sp[TR][NNODE + 2];           // stride 257
    int wv   = threadIdx.x >> 6;
    int lane = threadIdx.x & 63;
    int b0   = blockIdx.x * TR;
    int t    = threadIdx.x;

    // stage + sigmoid: 255*16 = 4080 logits
#pragma unroll
    for (int i = 0; i < 16; ++i) {
        int idx = i * 256 + t;
        if (idx < NNODE * TR) {
            int n = idx >> 4, bl = idx & 15;
            float lg = p_ws[(size_t)n * BATCH + b0 + bl];
            sp[bl][n] = __builtin_amdgcn_rcpf(1.f + __builtin_amdgcn_exp2f(-1.44269504088896f * lg));
        }
    }
    __syncthreads();

    // coalesced p_out copy
    for (int r = 0; r < TR; ++r)
        if (t < NNODE)
            p_out[(size_t)(b0 + r) * NNODE + t] = sp[r][t];

    // tree scan: 4 rows per wave; lane L owns leaves 4L..4L+3
    for (int rr = 0; rr < 4; ++rr) {
        int i = wv * 4 + rr;
        int b = b0 + i;
        const float* P = &sp[i][0];
        float* nr = nr_out + (size_t)b * NNODE;

        float pref = 1.f;
#pragma unroll
        for (int l = 0; l < 6; ++l) {
            if ((lane & ((1 << (6 - l)) - 1)) == 0) nr[(1 << l) - 1 + (lane >> (6 - l))] = pref;
            float pv  = P[(1 << l) - 1 + (lane >> (6 - l))];
            int  bit  = (lane >> (5 - l)) & 1;
            pref *= bit ? pv : (1.f - pv);
        }
        nr[63 + lane] = pref;
        float p6 = P[63 + lane];
        float pl = pref * (1.f - p6);
        float pr = pref * p6;
        nr[127 + 2 * lane] = pl;
        nr[128 + 2 * lane] = pr;
        float p7a = P[127 + 2 * lane];
        float p7b = P[128 + 2 * lane];
        float4 pp;
        pp.x = pl * (1.f - p7a);
        pp.y = pl * p7a;
        pp.z = pr * (1.f - p7b);
        pp.w = pr * p7b;
        *(float4*)(pp_out + (size_t)b * NLEAF + 4 * lane) = pp;
        const float4 lf = *(const float4*)(leaf + 4 * lane);
        float hs = pp.x * lf.x + pp.y * lf.y + pp.z * lf.z + pp.w * lf.w;
#pragma unroll
        for (int off = 1; off < 64; off <<= 1) hs += __shfl_xor(hs, off, 64);
        if (lane == 0) h_out[b] = hs;
    }
}

extern "C" void kernel_launch(void* const* d_in, const int* in_sizes, int n_in,
                              void* d_out, int out_size, void* d_ws, size_t ws_size,
                              hipStream_t stream) {
    const float* x    = (const float*)d_in[0];
    const float* W1   = (const float*)d_in[1];
    const float* b1   = (const float*)d_in[2];
    const float* W2   = (const float*)d_in[3];
    const float* b2   = (const float*)d_in[4];
    const float* leaf = (const float*)d_in[5];

    float* out    = (float*)d_out;
    float* h_out  = out;                                   // [16384]
    float* pp_out = out + BATCH;                           // [16384*256]
    float* p_out  = pp_out + (size_t)BATCH * NLEAF;        // [16384*255]
    float* nr_out = p_out + (size_t)BATCH * NNODE;         // [16384*255]

    // workspace: 4 MB xp + ~1 MB w1p + 16.7 MB logits
    half8* xp   = (half8*)d_ws;
    half8* w1p  = xp + (size_t)1024 * 4 * 64;
    float* p_ws = (float*)(w1p + (size_t)NNODE * 256);

    hipLaunchKernelGGL(k_pack_x,  dim3(1024),  dim3(256), 0, stream, x, xp);
    hipLaunchKernelGGL(k_pack_w1, dim3(NNODE), dim3(256), 0, stream, W1, w1p);
    hipLaunchKernelGGL(k_mlp,     dim3(128, 17), dim3(256), 0, stream, xp, w1p, b1, W2, b2, p_ws);
    hipLaunchKernelGGL(k_tree,    dim3(BATCH / TR), dim3(256), 0, stream,
                       p_ws, leaf, h_out, pp_out, p_out, nr_out);
}

// Round 7
// 124.948 us; speedup vs baseline: 1.0648x; 1.0526x over previous
//
#include <hip/hip_runtime.h>

// Problem constants (fixed by the reference).
#define BATCH 16384
#define DIN   128
#define HIDN  16
#define NNODE 255
#define NLEAF 256
#define TR    16          // batch rows per tree block

typedef _Float16 half8 __attribute__((ext_vector_type(8)));
typedef _Float16 half4 __attribute__((ext_vector_type(4)));
typedef float   float4v __attribute__((ext_vector_type(4)));

// ---------------- combined pack kernel ----------------
// blocks 0..1023: pack x -> f16 B-operand fragments
//   lane L holds B[k=(L>>4)*8+j][n=L&15] (n=batch, k=din); ws: [bt][kc][lane] half8
// blocks 1024..1278: pack W1[n] -> f16 A-operand fragments (LDS-staged)
//   lane L holds A[m=L&15][k=(L>>4)*8+j] (m=hidden, k=din); plus W2[n] -> f16
__global__ __launch_bounds__(256) void k_pack(const float* __restrict__ x, const float* __restrict__ w1,
                                              const float* __restrict__ w2,
                                              half8* __restrict__ xp, half8* __restrict__ w1p,
                                              _Float16* __restrict__ w2h) {
    __shared__ float w[DIN * 17];
    int t = threadIdx.x;
    if (blockIdx.x < 1024) {
        int gid  = blockIdx.x * 256 + t;
        int lane = gid & 63;
        int kc   = (gid >> 6) & 3;
        int bt   = gid >> 8;
        const float4* src = (const float4*)(x + (size_t)(bt * 16 + (lane & 15)) * DIN + kc * 32 + ((lane >> 4) * 8));
        float4 v0 = src[0], v1 = src[1];
        half8 v;
        v[0] = (_Float16)v0.x; v[1] = (_Float16)v0.y; v[2] = (_Float16)v0.z; v[3] = (_Float16)v0.w;
        v[4] = (_Float16)v1.x; v[5] = (_Float16)v1.y; v[6] = (_Float16)v1.z; v[7] = (_Float16)v1.w;
        xp[gid] = v;
    } else {
        int n = blockIdx.x - 1024;
        const float4* src = (const float4*)(w1 + (size_t)n * (DIN * HIDN)) + t * 2;
        float4 a0 = src[0], a1 = src[1];
        int base = t * 8;
#pragma unroll
        for (int e = 0; e < 4; ++e) {
            int idx0 = base + e, idx1 = base + 4 + e;
            w[(idx0 >> 4) * 17 + (idx0 & 15)] = (&a0.x)[e];
            w[(idx1 >> 4) * 17 + (idx1 & 15)] = (&a1.x)[e];
        }
        __syncthreads();
        int L  = t & 63;
        int kc = t >> 6;
        int m  = L & 15;
        int k0 = kc * 32 + (L >> 4) * 8;
        half8 v;
#pragma unroll
        for (int j = 0; j < 8; ++j) v[j] = (_Float16)w[(k0 + j) * 17 + m];
        w1p[(size_t)n * 256 + t] = v;
        if (t < HIDN) w2h[n * HIDN + t] = (_Float16)w2[n * HIDN + t];
    }
}

// ---------------- MLP: p_ws[n][b] = LOGIT via double MFMA ----------------
// MFMA-1 (A=W1, B=x^T): C[h=(L>>4)*4+reg][b=L&15]. relu+cvt gives EXACTLY the
// B-fragment of a 16x16x16 MFMA over k=h (lane L holds B[k=(L>>4)*4+j][n=L&15]).
// MFMA-2: A = W2[n][h] broadcast over m (lane L loads w2h[n*16+(L>>4)*4 .. +3]),
// C seeded with b2[n]. D: every lane's regs = logit[b=L&15] -> lanes 0..15 store
// one full 64B line. Zero cross-lane ops, no DS pipe, no sigmoid here.
__global__ __launch_bounds__(256, 4) void k_mlp(const half8* __restrict__ xp, const half8* __restrict__ w1p,
                                                const float* __restrict__ b1, const _Float16* __restrict__ w2h,
                                                const float* __restrict__ b2, float* __restrict__ p_ws) {
    int wv   = threadIdx.x >> 6;
    int lane = threadIdx.x & 63;
    int q    = lane >> 4;
    int bt0  = blockIdx.x * 16 + wv * 4;
    int n0   = blockIdx.y * 15;

    half8 bq[4][4];
#pragma unroll
    for (int t = 0; t < 4; ++t)
#pragma unroll
        for (int kc = 0; kc < 4; ++kc)
            bq[t][kc] = xp[(size_t)((bt0 + t) * 4 + kc) * 64 + lane];
    asm volatile("" ::: "memory");

    for (int i = 0; i < 15; ++i) {
        int n = n0 + i;
        half8 a[4];
#pragma unroll
        for (int kc = 0; kc < 4; ++kc) a[kc] = w1p[(size_t)(n * 4 + kc) * 64 + lane];
        float4 b1f = ((const float4*)(b1 + n * HIDN))[q];      // C1 seed: h = q*4+reg
        half4  a2  = *(const half4*)(w2h + n * HIDN + q * 4);  // A2 frag (W2 broadcast over m)
        float  b2v = b2[n];
#pragma unroll
        for (int t = 0; t < 4; ++t) {
            float4v acc = {b1f.x, b1f.y, b1f.z, b1f.w};
#pragma unroll
            for (int kc = 0; kc < 4; ++kc)
                acc = __builtin_amdgcn_mfma_f32_16x16x32_f16(a[kc], bq[t][kc], acc, 0, 0, 0);
            half4 rb;
#pragma unroll
            for (int r = 0; r < 4; ++r) rb[r] = (_Float16)fmaxf(acc[r], 0.f);
            float4v acc2 = {b2v, b2v, b2v, b2v};
            acc2 = __builtin_amdgcn_mfma_f32_16x16x16f16(a2, rb, acc2, 0, 0, 0);
            if (lane < 16)
                p_ws[(size_t)n * BATCH + (bt0 + t) * 16 + lane] = acc2[0];  // full 64B line
        }
    }
}

// ---------------- tree scan: sigmoid + all outputs, coalesced ----------------
// Block = 256 thr, 16 batch rows, LDS 16.4 KB (grid 1024 -> 4 blocks/CU).
__global__ __launch_bounds__(256) void k_tree(const float* __restrict__ p_ws, const float* __restrict__ leaf,
                                              float* __restrict__ h_out, float* __restrict__ pp_out,
                                              float* __restrict__ p_out, float* __restrict__ nr_out) {
    __shared__ float sp[TR][NNODE + 2];           // stride 257
    int wv   = threadIdx.x >> 6;
    int lane = threadIdx.x & 63;
    int b0   = blockIdx.x * TR;
    int t    = threadIdx.x;

    // stage + sigmoid: 255*16 = 4080 logits
#pragma unroll
    for (int i = 0; i < 16; ++i) {
        int idx = i * 256 + t;
        if (idx < NNODE * TR) {
            int n = idx >> 4, bl = idx & 15;
            float lg = p_ws[(size_t)n * BATCH + b0 + bl];
            sp[bl][n] = __builtin_amdgcn_rcpf(1.f + __builtin_amdgcn_exp2f(-1.44269504088896f * lg));
        }
    }
    __syncthreads();

    // coalesced p_out copy
    for (int r = 0; r < TR; ++r)
        if (t < NNODE)
            p_out[(size_t)(b0 + r) * NNODE + t] = sp[r][t];

    // tree scan: 4 rows per wave; lane L owns leaves 4L..4L+3
    for (int rr = 0; rr < 4; ++rr) {
        int i = wv * 4 + rr;
        int b = b0 + i;
        const float* P = &sp[i][0];
        float* nr = nr_out + (size_t)b * NNODE;

        float pref = 1.f;
#pragma unroll
        for (int l = 0; l < 6; ++l) {
            if ((lane & ((1 << (6 - l)) - 1)) == 0) nr[(1 << l) - 1 + (lane >> (6 - l))] = pref;
            float pv  = P[(1 << l) - 1 + (lane >> (6 - l))];
            int  bit  = (lane >> (5 - l)) & 1;
            pref *= bit ? pv : (1.f - pv);
        }
        nr[63 + lane] = pref;
        float p6 = P[63 + lane];
        float pl = pref * (1.f - p6);
        float pr = pref * p6;
        nr[127 + 2 * lane] = pl;
        nr[128 + 2 * lane] = pr;
        float p7a = P[127 + 2 * lane];
        float p7b = P[128 + 2 * lane];
        float4 pp;
        pp.x = pl * (1.f - p7a);
        pp.y = pl * p7a;
        pp.z = pr * (1.f - p7b);
        pp.w = pr * p7b;
        *(float4*)(pp_out + (size_t)b * NLEAF + 4 * lane) = pp;
        const float4 lf = *(const float4*)(leaf + 4 * lane);
        float hs = pp.x * lf.x + pp.y * lf.y + pp.z * lf.z + pp.w * lf.w;
#pragma unroll
        for (int off = 1; off < 64; off <<= 1) hs += __shfl_xor(hs, off, 64);
        if (lane == 0) h_out[b] = hs;
    }
}

extern "C" void kernel_launch(void* const* d_in, const int* in_sizes, int n_in,
                              void* d_out, int out_size, void* d_ws, size_t ws_size,
                              hipStream_t stream) {
    const float* x    = (const float*)d_in[0];
    const float* W1   = (const float*)d_in[1];
    const float* b1   = (const float*)d_in[2];
    const float* W2   = (const float*)d_in[3];
    const float* b2   = (const float*)d_in[4];
    const float* leaf = (const float*)d_in[5];

    float* out    = (float*)d_out;
    float* h_out  = out;                                   // [16384]
    float* pp_out = out + BATCH;                           // [16384*256]
    float* p_out  = pp_out + (size_t)BATCH * NLEAF;        // [16384*255]
    float* nr_out = p_out + (size_t)BATCH * NNODE;         // [16384*255]

    // workspace: 4 MB xp + ~1 MB w1p + 8 KB w2h + 16.7 MB logits
    half8*    xp   = (half8*)d_ws;
    half8*    w1p  = xp + (size_t)1024 * 4 * 64;
    _Float16* w2h  = (_Float16*)(w1p + (size_t)NNODE * 256);
    float*    p_ws = (float*)((char*)w2h + ((NNODE * HIDN * 2 + 255) & ~255));

    hipLaunchKernelGGL(k_pack, dim3(1024 + NNODE), dim3(256), 0, stream, x, W1, W2, xp, w1p, w2h);
    hipLaunchKernelGGL(k_mlp,  dim3(64, 17), dim3(256), 0, stream, xp, w1p, b1, w2h, b2, p_ws);
    hipLaunchKernelGGL(k_tree, dim3(BATCH / TR), dim3(256), 0, stream,
                       p_ws, leaf, h_out, pp_out, p_out, nr_out);
}